// Round 7
// baseline (424.164 us; speedup 1.0000x reference)
//
#include <hip/hip_runtime.h>
#include <cstdint>

typedef __attribute__((ext_vector_type(8))) short short8;
typedef __attribute__((ext_vector_type(4))) float f32x4;

#define THETA 0.7f
#define SCALE 0.17677669529663687f

__device__ __forceinline__ ushort f2b(float f) {
    uint32_t u = __float_as_uint(f);
    u += 0x7FFFu + ((u >> 16) & 1u);
    return (ushort)(u >> 16);
}
__device__ __forceinline__ float b2f(ushort b) {
    return __uint_as_float(((uint32_t)b) << 16);
}

typedef const __attribute__((address_space(1))) uint32_t* gas1_t;
typedef __attribute__((address_space(3))) uint32_t* las3_t;
__device__ __forceinline__ void gload16(const ushort* g, ushort* l) {
    __builtin_amdgcn_global_load_lds((gas1_t)g, (las3_t)l, 16, 0, 0);
}

// ---------------- K1: pad + cast + NCHW->NHWC transpose ----------------
__global__ __launch_bounds__(256) void k_pad(const float* __restrict__ x, ushort* __restrict__ xp) {
    int b = blockIdx.x >> 6, y = blockIdx.x & 63;
    int t = threadIdx.x;
    __shared__ float buf[64][65];
    for (int cc = 0; cc < 4; ++cc) {
        __syncthreads();
#pragma unroll
        for (int i = 0; i < 16; ++i) {
            int idx = i * 256 + t;
            int c = idx >> 6, xx = idx & 63;
            buf[c][xx] = x[(((size_t)b * 256 + cc * 64 + c) << 12) + (y << 6) + xx];
        }
        __syncthreads();
#pragma unroll
        for (int i = 0; i < 16; ++i) {
            int idx = i * 256 + t;
            int xx = idx >> 6, c = idx & 63;
            xp[((size_t)(b * 66 + y + 1) * 66 + (xx + 1)) * 256 + cc * 64 + c] = f2b(buf[c][xx]);
        }
    }
}

// ---------------- K2a: fold qkv weights ----------------
__global__ __launch_bounds__(256) void k_foldw(const float* __restrict__ w, const float* __restrict__ s,
                                               ushort* __restrict__ Wa) {
    int o = blockIdx.x, c = threadIdx.x;
    const float* wp = w + ((size_t)o * 256 + c) * 9;
    float v[9];
#pragma unroll
    for (int p = 0; p < 9; ++p) v[p] = wp[p];
    float hv = v[1] + v[3] + v[4] + v[5] + v[7];
    v[4] -= THETA * hv;
    float sc = s[o];
#pragma unroll
    for (int p = 0; p < 9; ++p)
        Wa[(size_t)o * 2304 + p * 256 + c] = f2b(v[p] * sc);
}

// ---------------- K2b: fold proj weights, hi/lo bf16 split, [o][c] ----------------
__global__ __launch_bounds__(256) void k_foldp(const float* __restrict__ w, const float* __restrict__ s,
                                               ushort* __restrict__ Wh, ushort* __restrict__ Wl) {
    int o = blockIdx.x, c = threadIdx.x;
    float v = w[(size_t)o * 256 + c] * s[o];
    ushort hi = f2b(v);
    Wh[(size_t)o * 256 + c] = hi;
    Wl[(size_t)o * 256 + c] = f2b(v - b2f(hi));
}

// ---------------- K3: qkv conv, implicit-im2col bf16 MFMA GEMM ----------------
// global_load_lds (width 16) double-buffered staging, linear [128][32] LDS,
// one barrier per K-step (m97/m151 pattern).
__global__ __launch_bounds__(256) void k_conv(const ushort* __restrict__ xp, const ushort* __restrict__ Wa,
                                              const float* __restrict__ qbias, ushort* __restrict__ qkv) {
    __shared__ ushort Abuf[2][4096];  // [buf][row*32+col], rows = 128 out-channels
    __shared__ ushort Bbuf[2][4096];  // [buf][row*32+col], rows = 128 pixels
    const int t = threadIdx.x;
    const int bid0 = blockIdx.x;
    const int bid = (bid0 & 7) * 192 + (bid0 >> 3);  // XCD swizzle: one batch per XCD
    const int b = bid / 192;
    const int ob = (bid % 192) >> 5;
    const int pb = bid & 31;
    const int o0 = ob << 7;
    const int lane = t & 63;
    const int w = t >> 6;
    const int y0 = pb * 2;
    const size_t xb = (size_t)b * 66 * 66 * 256;

    const int lrow = lane >> 2;        // 0..15: row within 16-row issue
    const int lcol8 = (lane & 3) << 3; // 0,8,16,24: element col

    // per-lane global source bases (match gload_lds lane*16B LDS order)
    const ushort* pA = Wa + (size_t)(o0 + w * 32 + lrow) * 2304 + lcol8;
    const ushort* pB = xp + xb + (size_t)((w & 1) * 32 + lrow) * 256 + lcol8;
    const int yrow = y0 + (w >> 1);

    f32x4 acc[4][4] = {};
    const int ow2 = (w >> 1) << 6;
    const int pw2 = (w & 1) << 6;
    const int fr = lane & 15;
    const int fs = (lane >> 4) << 3;

    auto stage = [&](int kn, int buf) {
        int pp = kn >> 3;
        int c0 = (kn & 7) << 5;
        int ky = pp / 3;
        int kx = pp - ky * 3;
        const ushort* ga = pA + kn * 32;
        const ushort* gb = pB + ((size_t)((yrow + ky) * 66 + kx)) * 256 + c0;
        ushort* la = &Abuf[buf][w * 1024];
        ushort* lb = &Bbuf[buf][w * 1024];
        gload16(ga, la);
        gload16(ga + 16 * 2304, la + 512);
        gload16(gb, lb);
        gload16(gb + 16 * 256, lb + 512);
    };

    stage(0, 0);
    for (int kn = 0; kn < 72; ++kn) {
        __syncthreads();  // drains vmcnt -> buf[kn&1] ready; prior reads of buf[(kn+1)&1] done
        if (kn < 71) stage(kn + 1, (kn + 1) & 1);
        const ushort* Ac = Abuf[kn & 1];
        const ushort* Bc = Bbuf[kn & 1];
        short8 af[4], bf[4];
#pragma unroll
        for (int i = 0; i < 4; ++i) af[i] = *(const short8*)&Ac[(ow2 + i * 16 + fr) * 32 + fs];
#pragma unroll
        for (int j = 0; j < 4; ++j) bf[j] = *(const short8*)&Bc[(pw2 + j * 16 + fr) * 32 + fs];
#pragma unroll
        for (int i = 0; i < 4; ++i)
#pragma unroll
            for (int j = 0; j < 4; ++j)
                acc[i][j] = __builtin_amdgcn_mfma_f32_16x16x32_bf16(af[i], bf[j], acc[i][j], 0, 0, 0);
    }
    const int pbase = pb * 128 + pw2 + (lane & 15);
#pragma unroll
    for (int i = 0; i < 4; ++i) {
        int o = o0 + ow2 + i * 16 + (lane >> 4) * 4;
#pragma unroll
        for (int r = 0; r < 4; ++r) {
            float bias = qbias[o + r];
            ushort* dst = qkv + ((size_t)b * 768 + o + r) * 4096 + pbase;
#pragma unroll
            for (int j = 0; j < 4; ++j)
                dst[j * 16] = f2b(acc[i][j][r] + bias);
        }
    }
}

// ---------------- K4: agent pooling, coalesced, bf16 in ----------------
__global__ __launch_bounds__(256) void k_pool(const ushort* __restrict__ qkv, float* __restrict__ ap) {
    const int bid = blockIdx.x;
    const int b = bid >> 8, c = bid & 255;
    const int t = threadIdx.x;
    const int y = t >> 2, xq = t & 3;
    __shared__ float lp[64][8];
    const ushort* qp = qkv + ((size_t)b * 768 + c) * 4096 + y * 64 + xq * 16;
    short8 a0 = *(const short8*)(qp);
    short8 a1 = *(const short8*)(qp + 8);
    float s0 = 0, s1 = 0;
#pragma unroll
    for (int j = 0; j < 8; ++j) s0 += b2f((ushort)a0[j]);
#pragma unroll
    for (int j = 0; j < 8; ++j) s1 += b2f((ushort)a1[j]);
    lp[y][xq * 2] = s0;
    lp[y][xq * 2 + 1] = s1;
    __syncthreads();
    if (t < 64) {
        int py = t >> 3, px = t & 7;
        float s = 0;
#pragma unroll
        for (int r = 0; r < 8; ++r) s += lp[py * 8 + r][px];
        ap[((size_t)b * 256 + c) * 64 + t] = s * (1.0f / 64.0f);
    }
}

// ---------------- K5: stage-1 attention partials, bf16 in ----------------
__global__ __launch_bounds__(256) void k_att1(const ushort* __restrict__ qkv, const float* __restrict__ ap,
                                              float* __restrict__ attn_g, float* __restrict__ s_g) {
    const int bid0 = blockIdx.x;
    const int bid = (bid0 & 7) * 64 + (bid0 >> 3);
    const int seg = bid & 7, h = (bid >> 3) & 7, b = bid >> 6;
    const int t = threadIdx.x;
    __shared__ float a_s[64][36];
    __shared__ ushort EL[256][68];
    __shared__ ushort vL[256][40];
#pragma unroll
    for (int i = 0; i < 8; ++i) {
        int idx = i * 256 + t;
        int n = idx & 63, d = idx >> 6;
        a_s[n][d] = ap[((size_t)b * 256 + h * 32 + d) * 64 + n] * SCALE;
    }
    const ushort* kb = qkv + ((size_t)b * 768 + 256 + h * 32) * 4096;
    const ushort* vb = qkv + ((size_t)b * 768 + 512 + h * 32) * 4096;
    const int n_own = t >> 2;
    const int dl = t & 3;
    float accr[8] = {0, 0, 0, 0, 0, 0, 0, 0};
    float s_acc = 0.f;
    __syncthreads();
    for (int chunk = 0; chunk < 2; ++chunk) {
        int pix = (seg * 2 + chunk) * 256 + t;
        float kr[32];
#pragma unroll
        for (int d = 0; d < 32; ++d) kr[d] = b2f(kb[(size_t)d * 4096 + pix]);
#pragma unroll
        for (int i = 0; i < 4; ++i) {
            uint4 pk;
            pk.x = (uint32_t)vb[(size_t)(8 * i + 0) * 4096 + pix] |
                   ((uint32_t)vb[(size_t)(8 * i + 1) * 4096 + pix] << 16);
            pk.y = (uint32_t)vb[(size_t)(8 * i + 2) * 4096 + pix] |
                   ((uint32_t)vb[(size_t)(8 * i + 3) * 4096 + pix] << 16);
            pk.z = (uint32_t)vb[(size_t)(8 * i + 4) * 4096 + pix] |
                   ((uint32_t)vb[(size_t)(8 * i + 5) * 4096 + pix] << 16);
            pk.w = (uint32_t)vb[(size_t)(8 * i + 6) * 4096 + pix] |
                   ((uint32_t)vb[(size_t)(8 * i + 7) * 4096 + pix] << 16);
            *(uint4*)&vL[t][i * 8] = pk;
        }
#pragma unroll 1
        for (int np = 0; np < 32; ++np) {
            float l0 = 0, l1 = 0;
#pragma unroll
            for (int dq = 0; dq < 8; ++dq) {
                f32x4 a0 = *(const f32x4*)&a_s[2 * np][dq * 4];
                f32x4 a1 = *(const f32x4*)&a_s[2 * np + 1][dq * 4];
                l0 += a0.x * kr[dq * 4] + a0.y * kr[dq * 4 + 1] + a0.z * kr[dq * 4 + 2] + a0.w * kr[dq * 4 + 3];
                l1 += a1.x * kr[dq * 4] + a1.y * kr[dq * 4 + 1] + a1.z * kr[dq * 4 + 2] + a1.w * kr[dq * 4 + 3];
            }
            uint32_t e2 = (uint32_t)f2b(__expf(l0)) | ((uint32_t)f2b(__expf(l1)) << 16);
            *(uint32_t*)&EL[t][2 * np] = e2;
        }
        __syncthreads();
#pragma unroll 1
        for (int tt = 0; tt < 256; ++tt) {
            float e = b2f(EL[tt][n_own]);
            if (dl == 0) s_acc += e;
            ushort4 va = *(const ushort4*)&vL[tt][dl * 8];
            ushort4 vbx = *(const ushort4*)&vL[tt][dl * 8 + 4];
            accr[0] += e * b2f(va.x);
            accr[1] += e * b2f(va.y);
            accr[2] += e * b2f(va.z);
            accr[3] += e * b2f(va.w);
            accr[4] += e * b2f(vbx.x);
            accr[5] += e * b2f(vbx.y);
            accr[6] += e * b2f(vbx.z);
            accr[7] += e * b2f(vbx.w);
        }
        __syncthreads();
    }
#pragma unroll
    for (int i = 0; i < 8; ++i)
        atomicAdd(&attn_g[(((size_t)b * 8 + h) * 64 + n_own) * 32 + dl * 8 + i], accr[i]);
    if (dl == 0) atomicAdd(&s_g[((size_t)b * 8 + h) * 64 + n_own], s_acc);
}

// ---------------- K6: stage-2 attention as two MFMA GEMMs ----------------
__global__ __launch_bounds__(256, 2) void k_att2(const ushort* __restrict__ qkv, const float* __restrict__ ap,
                                                 const float* __restrict__ attn_g, const float* __restrict__ s_g,
                                                 ushort* __restrict__ outp) {
    const int bid0 = blockIdx.x;
    const int bid = (bid0 & 7) * 256 + (bid0 >> 3);  // one batch per XCD
    const int ch = bid & 31, h = (bid >> 5) & 7, b = bid >> 8;
    const int t = threadIdx.x;
    const int lane = t & 63, w = t >> 6;
    const int fr = lane & 15, fs = (lane >> 4) << 3;
    const int pw = w << 5;
    const int pix0 = ch << 7;

    __shared__ ushort a_lds[64][40];  // A[n][d] * SCALE
    __shared__ ushort qt[128][40];    // Q^T[pix][d]
    __shared__ ushort pt[128][72];    // P^T[pix][n] (unnormalized exp)
    __shared__ ushort gh[32][72];     // G^T[d][n] hi
    __shared__ ushort gl[32][72];     // G^T[d][n] lo
    __shared__ float sInv[64];

#pragma unroll
    for (int i = 0; i < 8; ++i) {
        int e = i * 256 + t;
        int n = e & 63, d = e >> 6;
        a_lds[n][d] = f2b(ap[((size_t)b * 256 + h * 32 + d) * 64 + n] * SCALE);
    }
    if (t < 64) sInv[t] = 1.0f / s_g[((size_t)b * 8 + h) * 64 + t];
#pragma unroll
    for (int i = 0; i < 2; ++i) {
        int e = i * 256 + t;
        int d = e & 31, oc = e >> 5;
        const ushort* src = qkv + ((size_t)b * 768 + h * 32 + d) * 4096 + pix0 + oc * 8;
        short8 v = *(const short8*)src;
#pragma unroll
        for (int j2 = 0; j2 < 8; ++j2) qt[oc * 8 + j2][d] = (ushort)v[j2];
    }
    __syncthreads();

#pragma unroll
    for (int i = 0; i < 8; ++i) {
        int e = i * 256 + t;
        int n = e >> 5, d = e & 31;
        float g = attn_g[(((size_t)b * 8 + h) * 64 + n) * 32 + d] * sInv[n];
        ushort hi = f2b(g);
        gh[d][n] = hi;
        gl[d][n] = f2b(g - b2f(hi));
    }

    // L = A(64x32) x Q(32x128)
    f32x4 accL[4][2];
    {
        short8 af[4], bq[2];
#pragma unroll
        for (int i = 0; i < 4; ++i) af[i] = *(const short8*)&a_lds[i * 16 + fr][fs];
#pragma unroll
        for (int j = 0; j < 2; ++j) bq[j] = *(const short8*)&qt[pw + j * 16 + fr][fs];
#pragma unroll
        for (int i = 0; i < 4; ++i)
#pragma unroll
            for (int j = 0; j < 2; ++j) {
                f32x4 z = {0.f, 0.f, 0.f, 0.f};
                accL[i][j] = __builtin_amdgcn_mfma_f32_16x16x32_bf16(af[i], bq[j], z, 0, 0, 0);
            }
    }
    float sj[2];
#pragma unroll
    for (int j = 0; j < 2; ++j) {
        float s = 0.f;
        int pix = pw + j * 16 + fr;
#pragma unroll
        for (int i = 0; i < 4; ++i) {
            float e0 = __expf(accL[i][j][0]);
            float e1 = __expf(accL[i][j][1]);
            float e2 = __expf(accL[i][j][2]);
            float e3 = __expf(accL[i][j][3]);
            s += (e0 + e1) + (e2 + e3);
            int n0 = i * 16 + (lane >> 4) * 4;
            *(uint32_t*)&pt[pix][n0] = (uint32_t)f2b(e0) | ((uint32_t)f2b(e1) << 16);
            *(uint32_t*)&pt[pix][n0 + 2] = (uint32_t)f2b(e2) | ((uint32_t)f2b(e3) << 16);
        }
        s += __shfl_xor(s, 16);
        s += __shfl_xor(s, 32);
        sj[j] = 1.0f / s;
    }
    __syncthreads();

    // out = G^T(32x64) x P(64x128), hi+lo
    f32x4 accO[2][2] = {};
#pragma unroll
    for (int ks = 0; ks < 2; ++ks) {
        short8 gah[2], gal[2], pa[2];
#pragma unroll
        for (int dt = 0; dt < 2; ++dt) {
            gah[dt] = *(const short8*)&gh[dt * 16 + fr][ks * 32 + fs];
            gal[dt] = *(const short8*)&gl[dt * 16 + fr][ks * 32 + fs];
        }
#pragma unroll
        for (int j = 0; j < 2; ++j) pa[j] = *(const short8*)&pt[pw + j * 16 + fr][ks * 32 + fs];
#pragma unroll
        for (int dt = 0; dt < 2; ++dt)
#pragma unroll
            for (int j = 0; j < 2; ++j) {
                accO[dt][j] = __builtin_amdgcn_mfma_f32_16x16x32_bf16(gah[dt], pa[j], accO[dt][j], 0, 0, 0);
                accO[dt][j] = __builtin_amdgcn_mfma_f32_16x16x32_bf16(gal[dt], pa[j], accO[dt][j], 0, 0, 0);
            }
    }
#pragma unroll
    for (int dt = 0; dt < 2; ++dt)
#pragma unroll
        for (int j = 0; j < 2; ++j) {
            int pix = pix0 + pw + j * 16 + fr;
#pragma unroll
            for (int r = 0; r < 4; ++r) {
                int d = dt * 16 + (lane >> 4) * 4 + r;
                outp[((size_t)b * 256 + h * 32 + d) * 4096 + pix] = f2b(accO[dt][j][r] * sj[j]);
            }
        }
}

// ---------------- K7: depthwise 3x3 PE on v (bf16), RMW add into outp (bf16) ----------------
__global__ __launch_bounds__(256) void k_pe(const ushort* __restrict__ qkv, const float* __restrict__ pw,
                                            const float* __restrict__ ps, const float* __restrict__ pbias,
                                            ushort* __restrict__ outp) {
    int gid = blockIdx.x * 256 + threadIdx.x;  // [0, 2^21)
    int x4 = (gid & 15) << 2;
    int y = (gid >> 4) & 63;
    int c = (gid >> 10) & 255;
    int b = gid >> 18;
    const ushort* vp = qkv + ((size_t)b * 768 + 512 + c) * 4096;
    const float* wp = pw + c * 9;
    float s0 = 0, s1 = 0, s2 = 0, s3 = 0;
#pragma unroll
    for (int ky = 0; ky < 3; ++ky) {
        int yy = y + ky - 1;
        if ((unsigned)yy >= 64u) continue;
        const ushort* rp = vp + yy * 64 + x4;
        ushort4 m = *(const ushort4*)rp;
        float m0 = b2f(m.x), m1 = b2f(m.y), m2 = b2f(m.z), m3 = b2f(m.w);
        float lft = (x4 > 0) ? b2f(rp[-1]) : 0.f;
        float rgt = (x4 < 60) ? b2f(rp[4]) : 0.f;
        float w0 = wp[ky * 3], w1 = wp[ky * 3 + 1], w2 = wp[ky * 3 + 2];
        s0 += w0 * lft + w1 * m0 + w2 * m1;
        s1 += w0 * m0 + w1 * m1 + w2 * m2;
        s2 += w0 * m1 + w1 * m2 + w2 * m3;
        s3 += w0 * m2 + w1 * m3 + w2 * rgt;
    }
    float sc = ps[c], bb = pbias[c];
    ushort* op = outp + ((size_t)b * 256 + c) * 4096 + y * 64 + x4;
    ushort4 o = *(ushort4*)op;
    o.x = f2b(b2f(o.x) + sc * s0 + bb);
    o.y = f2b(b2f(o.y) + sc * s1 + bb);
    o.z = f2b(b2f(o.z) + sc * s2 + bb);
    o.w = f2b(b2f(o.w) + sc * s3 + bb);
    *(ushort4*)op = o;
}

// ---------------- K8: 1x1 projection as bf16 MFMA GEMM (hi/lo weights), bf16 in ----------------
__global__ __launch_bounds__(256) void k_proj(const ushort* __restrict__ outp, const ushort* __restrict__ Wh,
                                              const ushort* __restrict__ Wl, const float* __restrict__ pbias,
                                              float* __restrict__ out) {
    __shared__ ushort Ah[128][40];
    __shared__ ushort Alo[128][40];
    __shared__ ushort Xl[32][132];
    const int t = threadIdx.x;
    const int bid0 = blockIdx.x;
    const int bid = (bid0 & 7) * 64 + (bid0 >> 3);  // one batch per XCD
    const int b = bid >> 6;
    const int ob = (bid >> 5) & 1;
    const int pb = bid & 31;
    const int o0 = ob << 7;
    const int p0 = pb << 7;
    const int lane = t & 63;
    const int w = t >> 6;
    const int rw = t >> 2, q4 = t & 3;
    const int cl = t >> 3, pg = t & 7;
    const int ow2 = (w >> 1) << 6;
    const int pw2 = (w & 1) << 6;
    const int fr = lane & 15;
    const int fs = (lane >> 4) << 3;

    f32x4 acc[4][4] = {};
    uint4 rah0, rah1, ral0, ral1, rx0, rx1;
    auto loadk = [&](int kc) {
        const size_t awoff = (size_t)(o0 + rw) * 256 + kc * 32 + q4 * 8;
        rah0 = *(const uint4*)(Wh + awoff);
        rah1 = *(const uint4*)(Wh + awoff + (size_t)64 * 256);
        ral0 = *(const uint4*)(Wl + awoff);
        ral1 = *(const uint4*)(Wl + awoff + (size_t)64 * 256);
        const ushort* xsrc = outp + ((size_t)b * 256 + kc * 32 + cl) * 4096 + p0 + pg * 16;
        rx0 = *(const uint4*)xsrc;
        rx1 = *(const uint4*)(xsrc + 8);
    };
    loadk(0);
    for (int kc = 0; kc < 8; ++kc) {
        if (kc) __syncthreads();
        *(uint4*)&Ah[rw][q4 * 8] = rah0;
        *(uint4*)&Ah[rw + 64][q4 * 8] = rah1;
        *(uint4*)&Alo[rw][q4 * 8] = ral0;
        *(uint4*)&Alo[rw + 64][q4 * 8] = ral1;
        *(uint4*)&Xl[cl][pg * 16] = rx0;
        *(uint4*)&Xl[cl][pg * 16 + 8] = rx1;
        __syncthreads();
        if (kc < 7) loadk(kc + 1);
        short8 ah[4], al[4], bf[4];
#pragma unroll
        for (int i = 0; i < 4; ++i) {
            ah[i] = *(const short8*)&Ah[ow2 + i * 16 + fr][fs];
            al[i] = *(const short8*)&Alo[ow2 + i * 16 + fr][fs];
        }
#pragma unroll
        for (int j = 0; j < 4; ++j) {
            int pl = pw2 + j * 16 + fr;
#pragma unroll
            for (int kk = 0; kk < 8; ++kk) bf[j][kk] = (short)Xl[fs + kk][pl];
        }
#pragma unroll
        for (int i = 0; i < 4; ++i)
#pragma unroll
            for (int j = 0; j < 4; ++j) {
                acc[i][j] = __builtin_amdgcn_mfma_f32_16x16x32_bf16(ah[i], bf[j], acc[i][j], 0, 0, 0);
                acc[i][j] = __builtin_amdgcn_mfma_f32_16x16x32_bf16(al[i], bf[j], acc[i][j], 0, 0, 0);
            }
    }
    const int pbase = p0 + pw2 + (lane & 15);
#pragma unroll
    for (int i = 0; i < 4; ++i) {
        int o = o0 + ow2 + i * 16 + (lane >> 4) * 4;
#pragma unroll
        for (int r = 0; r < 4; ++r) {
            float bias = pbias[o + r];
            float* dst = out + ((size_t)b * 256 + o + r) * 4096 + pbase;
#pragma unroll
            for (int j = 0; j < 4; ++j)
                dst[j * 16] = acc[i][j][r] + bias;
        }
    }
}

extern "C" void kernel_launch(void* const* d_in, const int* in_sizes, int n_in,
                              void* d_out, int out_size, void* d_ws, size_t ws_size,
                              hipStream_t stream) {
    const float* x = (const float*)d_in[0];
    const float* qkv_w = (const float*)d_in[1];
    const float* qkv_s = (const float*)d_in[2];
    const float* qkv_b = (const float*)d_in[3];
    const float* pe_w = (const float*)d_in[4];
    const float* pe_s = (const float*)d_in[5];
    const float* pe_b = (const float*)d_in[6];
    const float* proj_w = (const float*)d_in[7];
    const float* proj_s = (const float*)d_in[8];
    const float* proj_b = (const float*)d_in[9];
    float* out = (float*)d_out;

    char* ws = (char*)d_ws;
    ushort* xp = (ushort*)(ws);                 // 17,842,176 B : padded NHWC bf16 input
    ushort* Wa = (ushort*)(ws + 17842176);      //  3,538,944 B : folded qkv weights bf16
    ushort* qkvb = (ushort*)(ws + 21381120);    // 50,331,648 B : qkv activations bf16
    float* apool = (float*)(ws + 71712768);     //    524,288 B : agent tokens f32
    float* attn_g = (float*)(ws + 72237056);    //    524,288 B : stage-1 partial numerators
    float* s_g = (float*)(ws + 72761344);       //     16,384 B : stage-1 partial denominators
    ushort* outpb = (ushort*)(ws + 72777728);   // 16,777,216 B : pre-projection output bf16
    ushort* Wh = (ushort*)(ws + 89554944);      //    131,072 B
    ushort* Wl = (ushort*)(ws + 89686016);      //    131,072 B

    hipMemsetAsync(xp, 0, 17842176, stream);
    hipMemsetAsync(attn_g, 0, 524288 + 16384, stream);
    k_pad<<<512, 256, 0, stream>>>(x, xp);
    k_foldw<<<768, 256, 0, stream>>>(qkv_w, qkv_s, Wa);
    k_foldp<<<256, 256, 0, stream>>>(proj_w, proj_s, Wh, Wl);
    k_conv<<<1536, 256, 0, stream>>>(xp, Wa, qkv_b, qkvb);
    k_pool<<<2048, 256, 0, stream>>>(qkvb, apool);
    k_att1<<<512, 256, 0, stream>>>(qkvb, apool, attn_g, s_g);
    k_att2<<<2048, 256, 0, stream>>>(qkvb, apool, attn_g, s_g, outpb);
    k_pe<<<8192, 256, 0, stream>>>(qkvb, pe_w, pe_s, pe_b, outpb);
    k_proj<<<512, 256, 0, stream>>>(outpb, Wh, Wl, proj_b, out);
}

// Round 8
// 390.119 us; speedup vs baseline: 1.0873x; 1.0873x over previous
//
#include <hip/hip_runtime.h>
#include <cstdint>

typedef __attribute__((ext_vector_type(8))) short short8;
typedef __attribute__((ext_vector_type(4))) float f32x4;

#define THETA 0.7f
#define SCALE 0.17677669529663687f

__device__ __forceinline__ ushort f2b(float f) {
    uint32_t u = __float_as_uint(f);
    u += 0x7FFFu + ((u >> 16) & 1u);
    return (ushort)(u >> 16);
}
__device__ __forceinline__ float b2f(ushort b) {
    return __uint_as_float(((uint32_t)b) << 16);
}

// ---------------- K1: pad + cast + NCHW->NHWC transpose ----------------
__global__ __launch_bounds__(256) void k_pad(const float* __restrict__ x, ushort* __restrict__ xp) {
    int b = blockIdx.x >> 6, y = blockIdx.x & 63;
    int t = threadIdx.x;
    __shared__ float buf[64][65];
    for (int cc = 0; cc < 4; ++cc) {
        __syncthreads();
#pragma unroll
        for (int i = 0; i < 16; ++i) {
            int idx = i * 256 + t;
            int c = idx >> 6, xx = idx & 63;
            buf[c][xx] = x[(((size_t)b * 256 + cc * 64 + c) << 12) + (y << 6) + xx];
        }
        __syncthreads();
#pragma unroll
        for (int i = 0; i < 16; ++i) {
            int idx = i * 256 + t;
            int xx = idx >> 6, c = idx & 63;
            xp[((size_t)(b * 66 + y + 1) * 66 + (xx + 1)) * 256 + cc * 64 + c] = f2b(buf[c][xx]);
        }
    }
}

// ---------------- K2a: fold qkv weights ----------------
__global__ __launch_bounds__(256) void k_foldw(const float* __restrict__ w, const float* __restrict__ s,
                                               ushort* __restrict__ Wa) {
    int o = blockIdx.x, c = threadIdx.x;
    const float* wp = w + ((size_t)o * 256 + c) * 9;
    float v[9];
#pragma unroll
    for (int p = 0; p < 9; ++p) v[p] = wp[p];
    float hv = v[1] + v[3] + v[4] + v[5] + v[7];
    v[4] -= THETA * hv;
    float sc = s[o];
#pragma unroll
    for (int p = 0; p < 9; ++p)
        Wa[(size_t)o * 2304 + p * 256 + c] = f2b(v[p] * sc);
}

// ---------------- K2b: fold proj weights, hi/lo bf16 split, [o][c] ----------------
__global__ __launch_bounds__(256) void k_foldp(const float* __restrict__ w, const float* __restrict__ s,
                                               ushort* __restrict__ Wh, ushort* __restrict__ Wl) {
    int o = blockIdx.x, c = threadIdx.x;
    float v = w[(size_t)o * 256 + c] * s[o];
    ushort hi = f2b(v);
    Wh[(size_t)o * 256 + c] = hi;
    Wl[(size_t)o * 256 + c] = f2b(v - b2f(hi));
}

// ---------------- K3: qkv conv as implicit-im2col bf16 MFMA GEMM, bf16 out ----------------
// (R6 version: register-prefetch staging — R7 gload_lds variant regressed 156->173us)
__global__ __launch_bounds__(256) void k_conv(const ushort* __restrict__ xp, const ushort* __restrict__ Wa,
                                              const float* __restrict__ qbias, ushort* __restrict__ qkv) {
    __shared__ ushort Al[128][40];
    __shared__ ushort Bl[128][40];
    const int t = threadIdx.x;
    const int bid0 = blockIdx.x;
    const int bid = (bid0 & 7) * 192 + (bid0 >> 3);  // XCD swizzle: one batch per XCD
    const int b = bid / 192;
    const int ob = (bid % 192) >> 5;
    const int pb = bid & 31;
    const int o0 = ob << 7;
    const int lane = t & 63;
    const int w = t >> 6;
    const int rw = t >> 2;
    const int q4 = t & 3;
    const ushort* Ag0 = Wa + (size_t)(o0 + rw) * 2304 + q4 * 8;
    const ushort* Ag1 = Ag0 + (size_t)64 * 2304;
    const int y0 = pb * 2;
    const size_t xb = (size_t)b * 66 * 66 * 256;

    f32x4 acc[4][4] = {};

    const int ow2 = (w >> 1) << 6;
    const int pw2 = (w & 1) << 6;
    const int fr = lane & 15;
    const int fs = (lane >> 4) << 3;

    uint4 ra0, ra1, rb0, rb1;
    auto loadk = [&](int kn) {
        int pp = kn >> 3;
        int c0 = (kn & 7) << 5;
        int ky = pp / 3, kx = pp - ky * 3;
        ra0 = *(const uint4*)(Ag0 + kn * 32);
        ra1 = *(const uint4*)(Ag1 + kn * 32);
        const ushort* bp = xp + xb + ((size_t)((y0 + ky) * 66 + (rw + kx))) * 256 + c0 + q4 * 8;
        rb0 = *(const uint4*)bp;
        rb1 = *(const uint4*)(bp + 66 * 256);
    };
    loadk(0);
    for (int kc = 0; kc < 72; ++kc) {
        if (kc) __syncthreads();
        *(uint4*)&Al[rw][q4 * 8] = ra0;
        *(uint4*)&Al[rw + 64][q4 * 8] = ra1;
        *(uint4*)&Bl[rw][q4 * 8] = rb0;
        *(uint4*)&Bl[rw + 64][q4 * 8] = rb1;
        __syncthreads();
        if (kc < 71) loadk(kc + 1);
        short8 af[4], bf[4];
#pragma unroll
        for (int i = 0; i < 4; ++i) af[i] = *(const short8*)&Al[ow2 + i * 16 + fr][fs];
#pragma unroll
        for (int j = 0; j < 4; ++j) bf[j] = *(const short8*)&Bl[pw2 + j * 16 + fr][fs];
#pragma unroll
        for (int i = 0; i < 4; ++i)
#pragma unroll
            for (int j = 0; j < 4; ++j)
                acc[i][j] = __builtin_amdgcn_mfma_f32_16x16x32_bf16(af[i], bf[j], acc[i][j], 0, 0, 0);
    }
    const int pbase = pb * 128 + pw2 + (lane & 15);
#pragma unroll
    for (int i = 0; i < 4; ++i) {
        int o = o0 + ow2 + i * 16 + (lane >> 4) * 4;
#pragma unroll
        for (int r = 0; r < 4; ++r) {
            float bias = qbias[o + r];
            ushort* dst = qkv + ((size_t)b * 768 + o + r) * 4096 + pbase;
#pragma unroll
            for (int j = 0; j < 4; ++j)
                dst[j * 16] = f2b(acc[i][j][r] + bias);
        }
    }
}

// ---------------- K4: agent pooling, coalesced, bf16 in ----------------
__global__ __launch_bounds__(256) void k_pool(const ushort* __restrict__ qkv, float* __restrict__ ap) {
    const int bid = blockIdx.x;
    const int b = bid >> 8, c = bid & 255;
    const int t = threadIdx.x;
    const int y = t >> 2, xq = t & 3;
    __shared__ float lp[64][8];
    const ushort* qp = qkv + ((size_t)b * 768 + c) * 4096 + y * 64 + xq * 16;
    short8 a0 = *(const short8*)(qp);
    short8 a1 = *(const short8*)(qp + 8);
    float s0 = 0, s1 = 0;
#pragma unroll
    for (int j = 0; j < 8; ++j) s0 += b2f((ushort)a0[j]);
#pragma unroll
    for (int j = 0; j < 8; ++j) s1 += b2f((ushort)a1[j]);
    lp[y][xq * 2] = s0;
    lp[y][xq * 2 + 1] = s1;
    __syncthreads();
    if (t < 64) {
        int py = t >> 3, px = t & 7;
        float s = 0;
#pragma unroll
        for (int r = 0; r < 8; ++r) s += lp[py * 8 + r][px];
        ap[((size_t)b * 256 + c) * 64 + t] = s * (1.0f / 64.0f);
    }
}

// ---------------- K5: stage-1 attention as two MFMA GEMMs ----------------
// Per block: one (b,h), 256-pixel segment. L[64n][256p] = A(64x32) x K^T;
// exp in-register; denom via shfl_xor column reduce; P->LDS [n][pix];
// attn partial = P x V^T with V b-frags read directly from global (natural [d][pix]).
// Partials accumulated with atomicAdd (no-max softmax, fully decomposable).
__global__ __launch_bounds__(256, 2) void k_att1(const ushort* __restrict__ qkv, const float* __restrict__ ap,
                                                 float* __restrict__ attn_g, float* __restrict__ s_g) {
    const int bid0 = blockIdx.x;
    const int bid = (bid0 & 7) * 128 + (bid0 >> 3);  // one batch per XCD
    const int seg = bid & 15, h = (bid >> 4) & 7, b = bid >> 7;
    const int t = threadIdx.x;
    const int lane = t & 63, w = t >> 6;
    const int fr = lane & 15, fs = (lane >> 4) << 3;
    const int g4 = (lane >> 4) << 2;
    const int pixseg = seg << 8;

    __shared__ ushort a_lds[64][40];  // A[n][d] * SCALE, bf16
    __shared__ ushort kt[256][40];    // K^T[pix][d]
    __shared__ ushort pt[64][264];    // P[n][pix] (unnormalized exp, bf16)

#pragma unroll
    for (int i = 0; i < 8; ++i) {
        int e = i * 256 + t;
        int n = e & 63, d = e >> 6;
        a_lds[n][d] = f2b(ap[((size_t)b * 256 + h * 32 + d) * 64 + n] * SCALE);
    }
    const ushort* kb = qkv + ((size_t)b * 768 + 256 + h * 32) * 4096;
    const ushort* vb = qkv + ((size_t)b * 768 + 512 + h * 32) * 4096;
#pragma unroll
    for (int i = 0; i < 4; ++i) {
        int e = i * 256 + t;
        int d = e & 31, oc = e >> 5;  // oc: 8-pixel group 0..31
        const ushort* src = kb + (size_t)d * 4096 + pixseg + oc * 8;
        short8 v = *(const short8*)src;
#pragma unroll
        for (int j2 = 0; j2 < 8; ++j2) kt[oc * 8 + j2][d] = (ushort)v[j2];
    }
    __syncthreads();

    // L = A(64x32) x K^T(32x256): wave w covers pixels w*64..w*64+63 (4 tiles)
    f32x4 accL[4][4];
    {
        short8 af[4], bq[4];
#pragma unroll
        for (int i = 0; i < 4; ++i) af[i] = *(const short8*)&a_lds[i * 16 + fr][fs];
#pragma unroll
        for (int j = 0; j < 4; ++j) bq[j] = *(const short8*)&kt[w * 64 + j * 16 + fr][fs];
#pragma unroll
        for (int i = 0; i < 4; ++i)
#pragma unroll
            for (int j = 0; j < 4; ++j) {
                f32x4 z = {0.f, 0.f, 0.f, 0.f};
                accL[i][j] = __builtin_amdgcn_mfma_f32_16x16x32_bf16(af[i], bq[j], z, 0, 0, 0);
            }
    }
    // exp, P -> LDS, per-n partial denominators (sum over this wave's 64 pixels)
    float sreg[4][4];  // [i][r] : n = i*16 + g4 + r
#pragma unroll
    for (int i = 0; i < 4; ++i)
#pragma unroll
        for (int r = 0; r < 4; ++r) sreg[i][r] = 0.f;
#pragma unroll
    for (int i = 0; i < 4; ++i)
#pragma unroll
        for (int j = 0; j < 4; ++j) {
            int pixl = w * 64 + j * 16 + fr;
#pragma unroll
            for (int r = 0; r < 4; ++r) {
                float e = __expf(accL[i][j][r]);
                sreg[i][r] += e;
                pt[i * 16 + g4 + r][pixl] = f2b(e);
            }
        }
    // reduce sreg over the 16 columns (lane&15) of each group
#pragma unroll
    for (int i = 0; i < 4; ++i)
#pragma unroll
        for (int r = 0; r < 4; ++r) {
            float s = sreg[i][r];
            s += __shfl_xor(s, 1);
            s += __shfl_xor(s, 2);
            s += __shfl_xor(s, 4);
            s += __shfl_xor(s, 8);
            sreg[i][r] = s;
        }
    if (fr == 0) {
#pragma unroll
        for (int i = 0; i < 4; ++i)
#pragma unroll
            for (int r = 0; r < 4; ++r)
                atomicAdd(&s_g[((size_t)b * 8 + h) * 64 + i * 16 + g4 + r], sreg[i][r]);
    }
    __syncthreads();

    // attn[64n][32d] partial = P(64 x 256) x V(32 x 256)^T; wave w takes k-range w*64..+63
    f32x4 accO[4][2] = {};
#pragma unroll
    for (int ks = 0; ks < 2; ++ks) {
        int pixk = w * 64 + ks * 32 + fs;
        short8 af[4], bf[2];
#pragma unroll
        for (int i = 0; i < 4; ++i) af[i] = *(const short8*)&pt[i * 16 + fr][pixk];
#pragma unroll
        for (int dt = 0; dt < 2; ++dt)
            bf[dt] = *(const short8*)(vb + (size_t)(dt * 16 + fr) * 4096 + pixseg + pixk);
#pragma unroll
        for (int i = 0; i < 4; ++i)
#pragma unroll
            for (int dt = 0; dt < 2; ++dt)
                accO[i][dt] = __builtin_amdgcn_mfma_f32_16x16x32_bf16(af[i], bf[dt], accO[i][dt], 0, 0, 0);
    }
#pragma unroll
    for (int i = 0; i < 4; ++i)
#pragma unroll
        for (int dt = 0; dt < 2; ++dt)
#pragma unroll
            for (int r = 0; r < 4; ++r) {
                int n = i * 16 + g4 + r;
                int d = dt * 16 + fr;
                atomicAdd(&attn_g[(((size_t)b * 8 + h) * 64 + n) * 32 + d], accO[i][dt][r]);
            }
}

// ---------------- K6: stage-2 attention as two MFMA GEMMs ----------------
__global__ __launch_bounds__(256, 2) void k_att2(const ushort* __restrict__ qkv, const float* __restrict__ ap,
                                                 const float* __restrict__ attn_g, const float* __restrict__ s_g,
                                                 ushort* __restrict__ outp) {
    const int bid0 = blockIdx.x;
    const int bid = (bid0 & 7) * 256 + (bid0 >> 3);  // one batch per XCD
    const int ch = bid & 31, h = (bid >> 5) & 7, b = bid >> 8;
    const int t = threadIdx.x;
    const int lane = t & 63, w = t >> 6;
    const int fr = lane & 15, fs = (lane >> 4) << 3;
    const int pw = w << 5;
    const int pix0 = ch << 7;

    __shared__ ushort a_lds[64][40];  // A[n][d] * SCALE
    __shared__ ushort qt[128][40];    // Q^T[pix][d]
    __shared__ ushort pt[128][72];    // P^T[pix][n] (unnormalized exp)
    __shared__ ushort gh[32][72];     // G^T[d][n] hi
    __shared__ ushort gl[32][72];     // G^T[d][n] lo
    __shared__ float sInv[64];

#pragma unroll
    for (int i = 0; i < 8; ++i) {
        int e = i * 256 + t;
        int n = e & 63, d = e >> 6;
        a_lds[n][d] = f2b(ap[((size_t)b * 256 + h * 32 + d) * 64 + n] * SCALE);
    }
    if (t < 64) sInv[t] = 1.0f / s_g[((size_t)b * 8 + h) * 64 + t];
#pragma unroll
    for (int i = 0; i < 2; ++i) {
        int e = i * 256 + t;
        int d = e & 31, oc = e >> 5;
        const ushort* src = qkv + ((size_t)b * 768 + h * 32 + d) * 4096 + pix0 + oc * 8;
        short8 v = *(const short8*)src;
#pragma unroll
        for (int j2 = 0; j2 < 8; ++j2) qt[oc * 8 + j2][d] = (ushort)v[j2];
    }
    __syncthreads();

#pragma unroll
    for (int i = 0; i < 8; ++i) {
        int e = i * 256 + t;
        int n = e >> 5, d = e & 31;
        float g = attn_g[(((size_t)b * 8 + h) * 64 + n) * 32 + d] * sInv[n];
        ushort hi = f2b(g);
        gh[d][n] = hi;
        gl[d][n] = f2b(g - b2f(hi));
    }

    // L = A(64x32) x Q(32x128)
    f32x4 accL[4][2];
    {
        short8 af[4], bq[2];
#pragma unroll
        for (int i = 0; i < 4; ++i) af[i] = *(const short8*)&a_lds[i * 16 + fr][fs];
#pragma unroll
        for (int j = 0; j < 2; ++j) bq[j] = *(const short8*)&qt[pw + j * 16 + fr][fs];
#pragma unroll
        for (int i = 0; i < 4; ++i)
#pragma unroll
            for (int j = 0; j < 2; ++j) {
                f32x4 z = {0.f, 0.f, 0.f, 0.f};
                accL[i][j] = __builtin_amdgcn_mfma_f32_16x16x32_bf16(af[i], bq[j], z, 0, 0, 0);
            }
    }
    float sj[2];
#pragma unroll
    for (int j = 0; j < 2; ++j) {
        float s = 0.f;
        int pix = pw + j * 16 + fr;
#pragma unroll
        for (int i = 0; i < 4; ++i) {
            float e0 = __expf(accL[i][j][0]);
            float e1 = __expf(accL[i][j][1]);
            float e2 = __expf(accL[i][j][2]);
            float e3 = __expf(accL[i][j][3]);
            s += (e0 + e1) + (e2 + e3);
            int n0 = i * 16 + (lane >> 4) * 4;
            *(uint32_t*)&pt[pix][n0] = (uint32_t)f2b(e0) | ((uint32_t)f2b(e1) << 16);
            *(uint32_t*)&pt[pix][n0 + 2] = (uint32_t)f2b(e2) | ((uint32_t)f2b(e3) << 16);
        }
        s += __shfl_xor(s, 16);
        s += __shfl_xor(s, 32);
        sj[j] = 1.0f / s;
    }
    __syncthreads();

    // out = G^T(32x64) x P(64x128), hi+lo
    f32x4 accO[2][2] = {};
#pragma unroll
    for (int ks = 0; ks < 2; ++ks) {
        short8 gah[2], gal[2], pa[2];
#pragma unroll
        for (int dt = 0; dt < 2; ++dt) {
            gah[dt] = *(const short8*)&gh[dt * 16 + fr][ks * 32 + fs];
            gal[dt] = *(const short8*)&gl[dt * 16 + fr][ks * 32 + fs];
        }
#pragma unroll
        for (int j = 0; j < 2; ++j) pa[j] = *(const short8*)&pt[pw + j * 16 + fr][ks * 32 + fs];
#pragma unroll
        for (int dt = 0; dt < 2; ++dt)
#pragma unroll
            for (int j = 0; j < 2; ++j) {
                accO[dt][j] = __builtin_amdgcn_mfma_f32_16x16x32_bf16(gah[dt], pa[j], accO[dt][j], 0, 0, 0);
                accO[dt][j] = __builtin_amdgcn_mfma_f32_16x16x32_bf16(gal[dt], pa[j], accO[dt][j], 0, 0, 0);
            }
    }
#pragma unroll
    for (int dt = 0; dt < 2; ++dt)
#pragma unroll
        for (int j = 0; j < 2; ++j) {
            int pix = pix0 + pw + j * 16 + fr;
#pragma unroll
            for (int r = 0; r < 4; ++r) {
                int d = dt * 16 + (lane >> 4) * 4 + r;
                outp[((size_t)b * 256 + h * 32 + d) * 4096 + pix] = f2b(accO[dt][j][r] * sj[j]);
            }
        }
}

// ---------------- K7: depthwise 3x3 PE on v (bf16), RMW add into outp (bf16) ----------------
__global__ __launch_bounds__(256) void k_pe(const ushort* __restrict__ qkv, const float* __restrict__ pw,
                                            const float* __restrict__ ps, const float* __restrict__ pbias,
                                            ushort* __restrict__ outp) {
    int gid = blockIdx.x * 256 + threadIdx.x;  // [0, 2^21)
    int x4 = (gid & 15) << 2;
    int y = (gid >> 4) & 63;
    int c = (gid >> 10) & 255;
    int b = gid >> 18;
    const ushort* vp = qkv + ((size_t)b * 768 + 512 + c) * 4096;
    const float* wp = pw + c * 9;
    float s0 = 0, s1 = 0, s2 = 0, s3 = 0;
#pragma unroll
    for (int ky = 0; ky < 3; ++ky) {
        int yy = y + ky - 1;
        if ((unsigned)yy >= 64u) continue;
        const ushort* rp = vp + yy * 64 + x4;
        ushort4 m = *(const ushort4*)rp;
        float m0 = b2f(m.x), m1 = b2f(m.y), m2 = b2f(m.z), m3 = b2f(m.w);
        float lft = (x4 > 0) ? b2f(rp[-1]) : 0.f;
        float rgt = (x4 < 60) ? b2f(rp[4]) : 0.f;
        float w0 = wp[ky * 3], w1 = wp[ky * 3 + 1], w2 = wp[ky * 3 + 2];
        s0 += w0 * lft + w1 * m0 + w2 * m1;
        s1 += w0 * m0 + w1 * m1 + w2 * m2;
        s2 += w0 * m1 + w1 * m2 + w2 * m3;
        s3 += w0 * m2 + w1 * m3 + w2 * rgt;
    }
    float sc = ps[c], bb = pbias[c];
    ushort* op = outp + ((size_t)b * 256 + c) * 4096 + y * 64 + x4;
    ushort4 o = *(ushort4*)op;
    o.x = f2b(b2f(o.x) + sc * s0 + bb);
    o.y = f2b(b2f(o.y) + sc * s1 + bb);
    o.z = f2b(b2f(o.z) + sc * s2 + bb);
    o.w = f2b(b2f(o.w) + sc * s3 + bb);
    *(ushort4*)op = o;
}

// ---------------- K8: 1x1 projection as bf16 MFMA GEMM (hi/lo weights), bf16 in ----------------
__global__ __launch_bounds__(256) void k_proj(const ushort* __restrict__ outp, const ushort* __restrict__ Wh,
                                              const ushort* __restrict__ Wl, const float* __restrict__ pbias,
                                              float* __restrict__ out) {
    __shared__ ushort Ah[128][40];
    __shared__ ushort Alo[128][40];
    __shared__ ushort Xl[32][132];
    const int t = threadIdx.x;
    const int bid0 = blockIdx.x;
    const int bid = (bid0 & 7) * 64 + (bid0 >> 3);  // one batch per XCD
    const int b = bid >> 6;
    const int ob = (bid >> 5) & 1;
    const int pb = bid & 31;
    const int o0 = ob << 7;
    const int p0 = pb << 7;
    const int lane = t & 63;
    const int w = t >> 6;
    const int rw = t >> 2, q4 = t & 3;
    const int cl = t >> 3, pg = t & 7;
    const int ow2 = (w >> 1) << 6;
    const int pw2 = (w & 1) << 6;
    const int fr = lane & 15;
    const int fs = (lane >> 4) << 3;

    f32x4 acc[4][4] = {};
    uint4 rah0, rah1, ral0, ral1, rx0, rx1;
    auto loadk = [&](int kc) {
        const size_t awoff = (size_t)(o0 + rw) * 256 + kc * 32 + q4 * 8;
        rah0 = *(const uint4*)(Wh + awoff);
        rah1 = *(const uint4*)(Wh + awoff + (size_t)64 * 256);
        ral0 = *(const uint4*)(Wl + awoff);
        ral1 = *(const uint4*)(Wl + awoff + (size_t)64 * 256);
        const ushort* xsrc = outp + ((size_t)b * 256 + kc * 32 + cl) * 4096 + p0 + pg * 16;
        rx0 = *(const uint4*)xsrc;
        rx1 = *(const uint4*)(xsrc + 8);
    };
    loadk(0);
    for (int kc = 0; kc < 8; ++kc) {
        if (kc) __syncthreads();
        *(uint4*)&Ah[rw][q4 * 8] = rah0;
        *(uint4*)&Ah[rw + 64][q4 * 8] = rah1;
        *(uint4*)&Alo[rw][q4 * 8] = ral0;
        *(uint4*)&Alo[rw + 64][q4 * 8] = ral1;
        *(uint4*)&Xl[cl][pg * 16] = rx0;
        *(uint4*)&Xl[cl][pg * 16 + 8] = rx1;
        __syncthreads();
        if (kc < 7) loadk(kc + 1);
        short8 ah[4], al[4], bf[4];
#pragma unroll
        for (int i = 0; i < 4; ++i) {
            ah[i] = *(const short8*)&Ah[ow2 + i * 16 + fr][fs];
            al[i] = *(const short8*)&Alo[ow2 + i * 16 + fr][fs];
        }
#pragma unroll
        for (int j = 0; j < 4; ++j) {
            int pl = pw2 + j * 16 + fr;
#pragma unroll
            for (int kk = 0; kk < 8; ++kk) bf[j][kk] = (short)Xl[fs + kk][pl];
        }
#pragma unroll
        for (int i = 0; i < 4; ++i)
#pragma unroll
            for (int j = 0; j < 4; ++j) {
                acc[i][j] = __builtin_amdgcn_mfma_f32_16x16x32_bf16(ah[i], bf[j], acc[i][j], 0, 0, 0);
                acc[i][j] = __builtin_amdgcn_mfma_f32_16x16x32_bf16(al[i], bf[j], acc[i][j], 0, 0, 0);
            }
    }
    const int pbase = p0 + pw2 + (lane & 15);
#pragma unroll
    for (int i = 0; i < 4; ++i) {
        int o = o0 + ow2 + i * 16 + (lane >> 4) * 4;
#pragma unroll
        for (int r = 0; r < 4; ++r) {
            float bias = pbias[o + r];
            float* dst = out + ((size_t)b * 256 + o + r) * 4096 + pbase;
#pragma unroll
            for (int j = 0; j < 4; ++j)
                dst[j * 16] = acc[i][j][r] + bias;
        }
    }
}

extern "C" void kernel_launch(void* const* d_in, const int* in_sizes, int n_in,
                              void* d_out, int out_size, void* d_ws, size_t ws_size,
                              hipStream_t stream) {
    const float* x = (const float*)d_in[0];
    const float* qkv_w = (const float*)d_in[1];
    const float* qkv_s = (const float*)d_in[2];
    const float* qkv_b = (const float*)d_in[3];
    const float* pe_w = (const float*)d_in[4];
    const float* pe_s = (const float*)d_in[5];
    const float* pe_b = (const float*)d_in[6];
    const float* proj_w = (const float*)d_in[7];
    const float* proj_s = (const float*)d_in[8];
    const float* proj_b = (const float*)d_in[9];
    float* out = (float*)d_out;

    char* ws = (char*)d_ws;
    ushort* xp = (ushort*)(ws);                 // 17,842,176 B : padded NHWC bf16 input
    ushort* Wa = (ushort*)(ws + 17842176);      //  3,538,944 B : folded qkv weights bf16
    ushort* qkvb = (ushort*)(ws + 21381120);    // 50,331,648 B : qkv activations bf16
    float* apool = (float*)(ws + 71712768);     //    524,288 B : agent tokens f32
    float* attn_g = (float*)(ws + 72237056);    //    524,288 B : stage-1 partial numerators
    float* s_g = (float*)(ws + 72761344);       //     16,384 B : stage-1 partial denominators
    ushort* outpb = (ushort*)(ws + 72777728);   // 16,777,216 B : pre-projection output bf16
    ushort* Wh = (ushort*)(ws + 89554944);      //    131,072 B
    ushort* Wl = (ushort*)(ws + 89686016);      //    131,072 B

    hipMemsetAsync(xp, 0, 17842176, stream);
    hipMemsetAsync(attn_g, 0, 524288 + 16384, stream);
    k_pad<<<512, 256, 0, stream>>>(x, xp);
    k_foldw<<<768, 256, 0, stream>>>(qkv_w, qkv_s, Wa);
    k_foldp<<<256, 256, 0, stream>>>(proj_w, proj_s, Wh, Wl);
    k_conv<<<1536, 256, 0, stream>>>(xp, Wa, qkv_b, qkvb);
    k_pool<<<2048, 256, 0, stream>>>(qkvb, apool);
    k_att1<<<1024, 256, 0, stream>>>(qkvb, apool, attn_g, s_g);
    k_att2<<<2048, 256, 0, stream>>>(qkvb, apool, attn_g, s_g, outpb);
    k_pe<<<8192, 256, 0, stream>>>(qkvb, pe_w, pe_s, pe_b, outpb);
    k_proj<<<512, 256, 0, stream>>>(outpb, Wh, Wl, proj_b, out);
}